// Round 1
// baseline (30496.301 us; speedup 1.0000x reference)
//
#include <hip/hip_runtime.h>
#include <stdint.h>

// Problem constants
#define T_  512
#define H_  256
#define B_  256
#define MB  16      // batch rows per group
#define NH  8       // workgroups (H-slices) per group; each owns 32 of the 256 h dims
#define NG  16      // groups = B_/MB
#define NWG (NG*NH) // 128 workgroups

typedef __attribute__((ext_vector_type(8))) short  short8;   // 8 bf16 = one MFMA A/B fragment
typedef __attribute__((ext_vector_type(4))) float  floatx4;  // MFMA C/D fragment

struct Params {
  const float* x;
  const float* Wih0; const float* Whh0; const float* bih0; const float* bhh0;
  const float* Wih1; const float* Whh1; const float* bih1; const float* bhh1;
  const float* Wih2; const float* Whh2; const float* bih2; const float* bhh2;
  const float* Wih3; const float* Whh3; const float* bih3; const float* bhh3;
  const float* fcW;  const float* fcb;
  unsigned* flags;   // 16 group barrier counters, 128B apart
  short* hbuf;       // [NG][2][MB][H_] bf16 double-buffered per-group h
  short* seq0;       // [B_][T_][H_] bf16 inter-layer sequence (ping)
  short* seq1;       // (pong)
};

__device__ __forceinline__ short f2bf(float f){
  uint32_t u = __builtin_bit_cast(uint32_t, f);
  u += 0x7fffu + ((u >> 16) & 1u);          // RNE
  return (short)(u >> 16);
}
__device__ __forceinline__ float bf2f(short s){
  uint32_t u = ((uint32_t)(uint16_t)s) << 16;
  return __builtin_bit_cast(float, u);
}
__device__ __forceinline__ float sigm(float v){ return 1.0f / (1.0f + __expf(-v)); }
__device__ __forceinline__ float tanh_(float v){
  // overflow-safe: e = exp(-2|v|) in (0,1]
  float a = fabsf(v);
  float e = __expf(-2.0f * a);
  float r = (1.0f - e) / (1.0f + e);
  return v < 0.0f ? -r : r;
}

#define MFMA(a,b,c) __builtin_amdgcn_mfma_f32_16x16x32_bf16((a),(b),(c),0,0,0)

// Persistent kernel: 128 WGs x 256 threads. Group = 8 WGs over one 16-row batch tile.
// Weights live in VGPRs as B-fragments; h all-gathered per step via global + device barrier.
__global__ __launch_bounds__(256, 1) void lstm_kernel(Params p){
  // A-fragments in exact MFMA fragment order: [kb][lane*8 .. lane*8+7] -> contiguous,
  // conflict-free b128 LDS reads/writes. kb 0..7 = x-part (K 0..255), 8..15 = h-part.
  __shared__ short a_frag[16 * 512];          // 16 KB
  __shared__ float g_lds[4][MB][33];          // gates i,f,g,o ; pad 33 vs 32
  __shared__ float bias_lds[4][32];           // b_ih + b_hh for this WG's 4x32 gate rows
  __shared__ float wih0_lds[4][32];           // layer-0 W_ih column (in_dim=1)
  __shared__ float x0_lds[MB];                // layer-0 x_t scalars

  const int tid   = threadIdx.x;
  const int lane  = tid & 63;
  const int wave  = tid >> 6;        // 0..3 == gate type i,f,g,o
  const int wg    = blockIdx.x;
  const int group = wg >> 3;         // 0..15
  const int slice = wg & 7;          // 0..7 -> h dims [slice*32, slice*32+32)
  const int b_base = group * MB;

  unsigned* cnt  = p.flags + group * 32;               // one cache line per group
  short*    hb_g = p.hbuf + group * (2 * MB * H_);

  // pointwise mapping: thread -> (batch row pm, two adjacent j's pj, pj+1)
  const int pm = tid >> 4;
  const int pj = (tid & 15) * 2;

  const int n15 = lane & 15;
  const int q4  = lane >> 4;

  for (int l = 0; l < 4; ++l){
    const float* WihL = (l==0)?p.Wih0 : (l==1)?p.Wih1 : (l==2)?p.Wih2 : p.Wih3;
    const float* WhhL = (l==0)?p.Whh0 : (l==1)?p.Whh1 : (l==2)?p.Whh2 : p.Whh3;
    const float* bihL = (l==0)?p.bih0 : (l==1)?p.bih1 : (l==2)?p.bih2 : p.bih3;
    const float* bhhL = (l==0)?p.bhh0 : (l==1)?p.bhh1 : (l==2)?p.bhh2 : p.bhh3;
    // layer l reads seq[(l-1)&1], writes seq[l&1] (layer 3 writes nothing; FC reads hbuf)
    const short* xin  = (l==1)?p.seq0 : (l==2)?p.seq1 : p.seq0;
    short*       xout = (l & 1) ? p.seq1 : p.seq0;

    __syncthreads();
    if (tid < 128){
      int gtype = tid >> 5, j = tid & 31;
      int g = gtype * 256 + slice * 32 + j;
      bias_lds[gtype][j] = bihL[g] + bhhL[g];
      if (l == 0) wih0_lds[gtype][j] = p.Wih0[g];   // W_ih0 is [1024 x 1]
    }

    // ---- Load weight B-fragments into VGPRs ----
    // Fused B[k][n], k in [0,512): k<256 -> W_ih (x path), k>=256 -> W_hh (h path).
    // Lane holds B[kb*32 + q4*8 + i][nb*16 + n15] = W[g][k'] , 8 consecutive k' per lane.
    short8 wf0[16], wf1[16];
    const int g0 = wave * 256 + slice * 32 + n15;        // nb=0
    const int g1 = wave * 256 + slice * 32 + 16 + n15;   // nb=1
    if (l == 0){
      #pragma unroll
      for (int kb = 0; kb < 8; ++kb){
        int kk = kb * 32 + q4 * 8;
        const float* p0 = WhhL + g0 * H_ + kk;
        const float* p1 = WhhL + g1 * H_ + kk;
        short8 a, b;
        #pragma unroll
        for (int i = 0; i < 8; ++i){ a[i] = f2bf(p0[i]); b[i] = f2bf(p1[i]); }
        wf0[kb] = a; wf1[kb] = b;
      }
    } else {
      #pragma unroll
      for (int kb = 0; kb < 16; ++kb){
        const float* base = (kb < 8) ? WihL : WhhL;
        int kk = ((kb < 8) ? kb * 32 : (kb - 8) * 32) + q4 * 8;
        const float* p0 = base + g0 * H_ + kk;
        const float* p1 = base + g1 * H_ + kk;
        short8 a, b;
        #pragma unroll
        for (int i = 0; i < 8; ++i){ a[i] = f2bf(p0[i]); b[i] = f2bf(p1[i]); }
        wf0[kb] = a; wf1[kb] = b;
      }
    }

    float c0 = 0.f, c1 = 0.f;                  // cell state, 2 elements per thread
    const int KBX = (l == 0) ? 0 : 8;          // where the h-part fragments live

    for (int t = 0; t < T_; ++t){
      // ---- Stage A fragments (distributed: each wave stages 2 h-kb and 2 x-kb) ----
      {
        #pragma unroll
        for (int kb2 = 0; kb2 < 2; ++kb2){
          int kb = wave * 2 + kb2;             // 0..7
          short8 v;
          if (t == 0){
            v = short8{0,0,0,0,0,0,0,0};
          } else {
            const short* hp = hb_g + ((t-1)&1) * (MB*H_) + n15 * H_ + kb * 32 + q4 * 8;
            v = *(const short8*)hp;
          }
          *(short8*)&a_frag[(KBX + kb) * 512 + lane * 8] = v;
        }
        if (l > 0){
          #pragma unroll
          for (int kb2 = 0; kb2 < 2; ++kb2){
            int kb = wave * 2 + kb2;
            const short* xp = xin + ((long)(b_base + n15) * T_ + t) * H_ + kb * 32 + q4 * 8;
            *(short8*)&a_frag[kb * 512 + lane * 8] = *(const short8*)xp;
          }
        } else if (wave == 0 && lane < MB){
          x0_lds[lane] = p.x[(b_base + lane) * T_ + t];
        }
      }
      __syncthreads();

      // ---- MFMA: gates[m][n] = sum_k A[m][k] * B[k][n], 2 n-blocks, split-k chains ----
      floatx4 a0e = {0,0,0,0}, a0o = {0,0,0,0}, a1e = {0,0,0,0}, a1o = {0,0,0,0};
      if (l == 0){
        #pragma unroll
        for (int kb = 0; kb < 8; ++kb){
          short8 af = *(short8*)&a_frag[kb * 512 + lane * 8];
          if (kb & 1){ a0o = MFMA(af, wf0[kb], a0o); a1o = MFMA(af, wf1[kb], a1o); }
          else       { a0e = MFMA(af, wf0[kb], a0e); a1e = MFMA(af, wf1[kb], a1e); }
        }
      } else {
        #pragma unroll
        for (int kb = 0; kb < 16; ++kb){
          short8 af = *(short8*)&a_frag[kb * 512 + lane * 8];
          if (kb & 1){ a0o = MFMA(af, wf0[kb], a0o); a1o = MFMA(af, wf1[kb], a1o); }
          else       { a0e = MFMA(af, wf0[kb], a0e); a1e = MFMA(af, wf1[kb], a1e); }
        }
      }
      floatx4 acc0 = a0e + a0o;
      floatx4 acc1 = a1e + a1o;

      // ---- Write gates to LDS (D layout: m = q4*4+r, n = lane&15) ----
      {
        int mq = q4 * 4;
        #pragma unroll
        for (int r = 0; r < 4; ++r){
          g_lds[wave][mq + r][n15]      = acc0[r];
          g_lds[wave][mq + r][16 + n15] = acc1[r];
        }
      }
      __syncthreads();

      // ---- Pointwise: gates -> c,h (fp32), store h (bf16) ----
      {
        float gA0 = g_lds[0][pm][pj]   + bias_lds[0][pj];
        float gA1 = g_lds[0][pm][pj+1] + bias_lds[0][pj+1];
        float gB0 = g_lds[1][pm][pj]   + bias_lds[1][pj];
        float gB1 = g_lds[1][pm][pj+1] + bias_lds[1][pj+1];
        float gC0 = g_lds[2][pm][pj]   + bias_lds[2][pj];
        float gC1 = g_lds[2][pm][pj+1] + bias_lds[2][pj+1];
        float gD0 = g_lds[3][pm][pj]   + bias_lds[3][pj];
        float gD1 = g_lds[3][pm][pj+1] + bias_lds[3][pj+1];
        if (l == 0){
          float xs = x0_lds[pm];
          gA0 += xs * wih0_lds[0][pj]; gA1 += xs * wih0_lds[0][pj+1];
          gB0 += xs * wih0_lds[1][pj]; gB1 += xs * wih0_lds[1][pj+1];
          gC0 += xs * wih0_lds[2][pj]; gC1 += xs * wih0_lds[2][pj+1];
          gD0 += xs * wih0_lds[3][pj]; gD1 += xs * wih0_lds[3][pj+1];
        }
        float i0 = sigm(gA0), i1 = sigm(gA1);
        float f0 = sigm(gB0), f1 = sigm(gB1);
        float g0v = tanh_(gC0), g1v = tanh_(gC1);
        float o0 = sigm(gD0), o1 = sigm(gD1);
        c0 = f0 * c0 + i0 * g0v;
        c1 = f1 * c1 + i1 * g1v;
        float h0 = o0 * tanh_(c0);
        float h1 = o1 * tanh_(c1);
        uint32_t pk = (uint32_t)(uint16_t)f2bf(h0) | ((uint32_t)(uint16_t)f2bf(h1) << 16);
        *(uint32_t*)(hb_g + (t & 1) * (MB*H_) + pm * H_ + slice * 32 + pj) = pk;
        if (l < 3){
          *(uint32_t*)(xout + ((long)(b_base + pm) * T_ + t) * H_ + slice * 32 + pj) = pk;
        }
      }

      // ---- Group barrier (device scope): release writes, all-8 arrive, acquire ----
      __threadfence();
      __syncthreads();
      if (tid == 0){
        unsigned target = (unsigned)(l * T_ + t + 1) * NH;
        __hip_atomic_fetch_add(cnt, 1u, __ATOMIC_RELEASE, __HIP_MEMORY_SCOPE_AGENT);
        int guard = 0;
        while (__hip_atomic_load(cnt, __ATOMIC_ACQUIRE, __HIP_MEMORY_SCOPE_AGENT) < target){
          __builtin_amdgcn_s_sleep(1);
          if (++guard > (1 << 21)) break;   // anti-hang bailout
        }
      }
      __syncthreads();
    } // t
  } // l
}

// Final FC on last-timestep h of layer 3 (sitting in hbuf parity 1).
__global__ void fc_kernel(const short* __restrict__ hbuf, const float* __restrict__ fcW,
                          const float* __restrict__ fcb, float* __restrict__ out){
  int b = blockIdx.x;               // 0..255
  int lane = threadIdx.x;           // 64
  int grp = b >> 4, m = b & 15;
  const short* hp = hbuf + grp * (2 * MB * H_) + (MB * H_) + m * H_;  // (T-1)&1 == 1
  float s = 0.f;
  #pragma unroll
  for (int k = 0; k < 4; ++k){
    int j = lane + 64 * k;
    s += bf2f(hp[j]) * fcW[j];
  }
  #pragma unroll
  for (int off = 32; off; off >>= 1) s += __shfl_down(s, off);
  if (lane == 0) out[b] = s + fcb[0];
}

extern "C" void kernel_launch(void* const* d_in, const int* in_sizes, int n_in,
                              void* d_out, int out_size, void* d_ws, size_t ws_size,
                              hipStream_t stream) {
  Params P;
  P.x    = (const float*)d_in[0];
  P.Wih0 = (const float*)d_in[1];  P.Whh0 = (const float*)d_in[2];
  P.bih0 = (const float*)d_in[3];  P.bhh0 = (const float*)d_in[4];
  P.Wih1 = (const float*)d_in[5];  P.Whh1 = (const float*)d_in[6];
  P.bih1 = (const float*)d_in[7];  P.bhh1 = (const float*)d_in[8];
  P.Wih2 = (const float*)d_in[9];  P.Whh2 = (const float*)d_in[10];
  P.bih2 = (const float*)d_in[11]; P.bhh2 = (const float*)d_in[12];
  P.Wih3 = (const float*)d_in[13]; P.Whh3 = (const float*)d_in[14];
  P.bih3 = (const float*)d_in[15]; P.bhh3 = (const float*)d_in[16];
  P.fcW  = (const float*)d_in[17]; P.fcb  = (const float*)d_in[18];

  char* ws = (char*)d_ws;
  P.flags = (unsigned*)ws;                               // 2 KB used
  P.hbuf  = (short*)(ws + 4096);                         // 256 KB
  const size_t SEQ_BYTES = (size_t)B_ * T_ * H_ * 2;     // 64 MB
  P.seq0  = (short*)(ws + (1 << 20));
  P.seq1  = (short*)(ws + (1 << 20) + SEQ_BYTES);

  hipMemsetAsync(P.flags, 0, 4096, stream);
  hipLaunchKernelGGL(lstm_kernel, dim3(NWG), dim3(256), 0, stream, P);
  hipLaunchKernelGGL(fc_kernel, dim3(B_), dim3(64), 0, stream,
                     P.hbuf, P.fcW, P.fcb, (float*)d_out);
}

// Round 2
// 7062.511 us; speedup vs baseline: 4.3181x; 4.3181x over previous
//
#include <hip/hip_runtime.h>
#include <stdint.h>

// Problem constants
#define T_  512
#define H_  256
#define B_  256
#define MB  16      // batch rows per group
#define NH  8       // workgroups (H-slices) per group; each owns 32 of the 256 h dims
#define NG  16      // groups = B_/MB
#define NWG (NG*NH) // 128 workgroups

typedef __attribute__((ext_vector_type(8))) short  short8;   // 8 bf16 = one MFMA A/B fragment
typedef __attribute__((ext_vector_type(4))) float  floatx4;  // MFMA C/D fragment

struct Params {
  const float* x;
  const float* Wih0; const float* Whh0; const float* bih0; const float* bhh0;
  const float* Wih1; const float* Whh1; const float* bih1; const float* bhh1;
  const float* Wih2; const float* Whh2; const float* bih2; const float* bhh2;
  const float* Wih3; const float* Whh3; const float* bih3; const float* bhh3;
  const float* fcW;  const float* fcb;
  unsigned* flags;   // per group: 64 dwords; [slice] = last completed step id
  short* hbuf;       // [NG][2][MB][H_] bf16 double-buffered per-group h
  short* seq0;       // [B_][T_][H_] bf16 inter-layer sequence (ping)
  short* seq1;       // (pong)
};

__device__ __forceinline__ short f2bf(float f){
  uint32_t u = __builtin_bit_cast(uint32_t, f);
  u += 0x7fffu + ((u >> 16) & 1u);          // RNE
  return (short)(u >> 16);
}
__device__ __forceinline__ float bf2f(short s){
  uint32_t u = ((uint32_t)(uint16_t)s) << 16;
  return __builtin_bit_cast(float, u);
}
__device__ __forceinline__ float sigm(float v){ return 1.0f / (1.0f + __expf(-v)); }
__device__ __forceinline__ float tanh_(float v){
  float a = fabsf(v);
  float e = __expf(-2.0f * a);
  float r = (1.0f - e) / (1.0f + e);
  return v < 0.0f ? -r : r;
}

// L3-coherent (cache-bypassing) relaxed atomics — no buffer_wbl2/buffer_inv fences.
__device__ __forceinline__ unsigned long long ld_u64(const unsigned long long* p){
  return __hip_atomic_load(p, __ATOMIC_RELAXED, __HIP_MEMORY_SCOPE_AGENT);
}
__device__ __forceinline__ void st_u32(unsigned* p, unsigned v){
  __hip_atomic_store(p, v, __ATOMIC_RELAXED, __HIP_MEMORY_SCOPE_AGENT);
}
__device__ __forceinline__ unsigned ld_u32(const unsigned* p){
  return __hip_atomic_load(p, __ATOMIC_RELAXED, __HIP_MEMORY_SCOPE_AGENT);
}

#define MFMA(a,b,c) __builtin_amdgcn_mfma_f32_16x16x32_bf16((a),(b),(c),0,0,0)

__global__ __launch_bounds__(256, 1) void lstm_kernel(Params p){
  __shared__ short a_frag[16 * 512];          // 16 KB, exact MFMA A-fragment order
  __shared__ float g_lds[4][MB][33];          // gates i,f,g,o ; pad 33 vs 32
  __shared__ float bias_lds[4][32];
  __shared__ float wih0_lds[4][32];
  __shared__ float x0_lds[MB];

  const int tid   = threadIdx.x;
  const int lane  = tid & 63;
  const int wave  = tid >> 6;        // 0..3 == gate type i,f,g,o
  const int wg    = blockIdx.x;
  const int group = wg >> 3;         // 0..15
  const int slice = wg & 7;          // 0..7 -> h dims [slice*32, slice*32+32)
  const int b_base = group * MB;

  unsigned* flags = p.flags + group * 64;              // 256B per group
  short*    hb_g  = p.hbuf + group * (2 * MB * H_);

  const int pm = tid >> 4;           // pointwise: batch row
  const int pj = (tid & 15) * 2;     // pointwise: two adjacent h dims

  const int n15 = lane & 15;
  const int q4  = lane >> 4;

  bool dead = false;                 // barrier-timeout bailout

  for (int l = 0; l < 4; ++l){
    const float* WihL = (l==0)?p.Wih0 : (l==1)?p.Wih1 : (l==2)?p.Wih2 : p.Wih3;
    const float* WhhL = (l==0)?p.Whh0 : (l==1)?p.Whh1 : (l==2)?p.Whh2 : p.Whh3;
    const float* bihL = (l==0)?p.bih0 : (l==1)?p.bih1 : (l==2)?p.bih2 : p.bih3;
    const float* bhhL = (l==0)?p.bhh0 : (l==1)?p.bhh1 : (l==2)?p.bhh2 : p.bhh3;
    const short* xin  = (l==1)?p.seq0 : (l==2)?p.seq1 : p.seq0;
    short*       xout = (l & 1) ? p.seq1 : p.seq0;

    __syncthreads();
    if (tid < 128){
      int gtype = tid >> 5, j = tid & 31;
      int g = gtype * 256 + slice * 32 + j;
      bias_lds[gtype][j] = bihL[g] + bhhL[g];
      if (l == 0) wih0_lds[gtype][j] = p.Wih0[g];
    }

    // ---- Load weight B-fragments into VGPRs (plain cached loads, read-only) ----
    short8 wf0[16], wf1[16];
    const int g0 = wave * 256 + slice * 32 + n15;        // nb=0
    const int g1 = wave * 256 + slice * 32 + 16 + n15;   // nb=1
    if (l == 0){
      #pragma unroll
      for (int kb = 0; kb < 8; ++kb){
        int kk = kb * 32 + q4 * 8;
        const float* p0 = WhhL + g0 * H_ + kk;
        const float* p1 = WhhL + g1 * H_ + kk;
        short8 a, b;
        #pragma unroll
        for (int i = 0; i < 8; ++i){ a[i] = f2bf(p0[i]); b[i] = f2bf(p1[i]); }
        wf0[kb] = a; wf1[kb] = b;
      }
    } else {
      #pragma unroll
      for (int kb = 0; kb < 16; ++kb){
        const float* base = (kb < 8) ? WihL : WhhL;
        int kk = ((kb < 8) ? kb * 32 : (kb - 8) * 32) + q4 * 8;
        const float* p0 = base + g0 * H_ + kk;
        const float* p1 = base + g1 * H_ + kk;
        short8 a, b;
        #pragma unroll
        for (int i = 0; i < 8; ++i){ a[i] = f2bf(p0[i]); b[i] = f2bf(p1[i]); }
        wf0[kb] = a; wf1[kb] = b;
      }
    }

    float c0 = 0.f, c1 = 0.f;
    const int KBX = (l == 0) ? 0 : 8;

    for (int t = 0; t < T_; ++t){
      // ---- Stage A fragments: issue ALL L3 loads first, then LDS stores ----
      {
        unsigned long long hv[4];            // 2 h-kbs x 2 halves
        unsigned long long xv[4];            // 2 x-kbs x 2 halves (l>0)
        const int kbA = wave * 2, kbB = wave * 2 + 1;
        if (t > 0){
          const unsigned long long* hpA = (const unsigned long long*)
            (hb_g + ((t-1)&1) * (MB*H_) + n15 * H_ + kbA * 32 + q4 * 8);
          const unsigned long long* hpB = (const unsigned long long*)
            (hb_g + ((t-1)&1) * (MB*H_) + n15 * H_ + kbB * 32 + q4 * 8);
          hv[0] = ld_u64(hpA); hv[1] = ld_u64(hpA + 1);
          hv[2] = ld_u64(hpB); hv[3] = ld_u64(hpB + 1);
        } else {
          hv[0] = hv[1] = hv[2] = hv[3] = 0ull;
        }
        if (l > 0){
          const unsigned long long* xpA = (const unsigned long long*)
            (xin + ((long)(b_base + n15) * T_ + t) * H_ + kbA * 32 + q4 * 8);
          const unsigned long long* xpB = (const unsigned long long*)
            (xin + ((long)(b_base + n15) * T_ + t) * H_ + kbB * 32 + q4 * 8);
          xv[0] = ld_u64(xpA); xv[1] = ld_u64(xpA + 1);
          xv[2] = ld_u64(xpB); xv[3] = ld_u64(xpB + 1);
        }
        unsigned long long* dA = (unsigned long long*)&a_frag[(KBX + kbA) * 512 + lane * 8];
        unsigned long long* dB = (unsigned long long*)&a_frag[(KBX + kbB) * 512 + lane * 8];
        dA[0] = hv[0]; dA[1] = hv[1];
        dB[0] = hv[2]; dB[1] = hv[3];
        if (l > 0){
          unsigned long long* eA = (unsigned long long*)&a_frag[kbA * 512 + lane * 8];
          unsigned long long* eB = (unsigned long long*)&a_frag[kbB * 512 + lane * 8];
          eA[0] = xv[0]; eA[1] = xv[1];
          eB[0] = xv[2]; eB[1] = xv[3];
        } else if (wave == 0 && lane < MB){
          x0_lds[lane] = p.x[(b_base + lane) * T_ + t];
        }
      }
      __syncthreads();

      // ---- MFMA ----
      floatx4 a0e = {0,0,0,0}, a0o = {0,0,0,0}, a1e = {0,0,0,0}, a1o = {0,0,0,0};
      if (l == 0){
        #pragma unroll
        for (int kb = 0; kb < 8; ++kb){
          short8 af = *(short8*)&a_frag[kb * 512 + lane * 8];
          if (kb & 1){ a0o = MFMA(af, wf0[kb], a0o); a1o = MFMA(af, wf1[kb], a1o); }
          else       { a0e = MFMA(af, wf0[kb], a0e); a1e = MFMA(af, wf1[kb], a1e); }
        }
      } else {
        #pragma unroll
        for (int kb = 0; kb < 16; ++kb){
          short8 af = *(short8*)&a_frag[kb * 512 + lane * 8];
          if (kb & 1){ a0o = MFMA(af, wf0[kb], a0o); a1o = MFMA(af, wf1[kb], a1o); }
          else       { a0e = MFMA(af, wf0[kb], a0e); a1e = MFMA(af, wf1[kb], a1e); }
        }
      }
      floatx4 acc0 = a0e + a0o;
      floatx4 acc1 = a1e + a1o;

      {
        int mq = q4 * 4;
        #pragma unroll
        for (int r = 0; r < 4; ++r){
          g_lds[wave][mq + r][n15]      = acc0[r];
          g_lds[wave][mq + r][16 + n15] = acc1[r];
        }
      }
      __syncthreads();

      // ---- Pointwise ----
      {
        float gA0 = g_lds[0][pm][pj]   + bias_lds[0][pj];
        float gA1 = g_lds[0][pm][pj+1] + bias_lds[0][pj+1];
        float gB0 = g_lds[1][pm][pj]   + bias_lds[1][pj];
        float gB1 = g_lds[1][pm][pj+1] + bias_lds[1][pj+1];
        float gC0 = g_lds[2][pm][pj]   + bias_lds[2][pj];
        float gC1 = g_lds[2][pm][pj+1] + bias_lds[2][pj+1];
        float gD0 = g_lds[3][pm][pj]   + bias_lds[3][pj];
        float gD1 = g_lds[3][pm][pj+1] + bias_lds[3][pj+1];
        if (l == 0){
          float xs = x0_lds[pm];
          gA0 += xs * wih0_lds[0][pj]; gA1 += xs * wih0_lds[0][pj+1];
          gB0 += xs * wih0_lds[1][pj]; gB1 += xs * wih0_lds[1][pj+1];
          gC0 += xs * wih0_lds[2][pj]; gC1 += xs * wih0_lds[2][pj+1];
          gD0 += xs * wih0_lds[3][pj]; gD1 += xs * wih0_lds[3][pj+1];
        }
        float i0 = sigm(gA0), i1 = sigm(gA1);
        float f0 = sigm(gB0), f1 = sigm(gB1);
        float g0v = tanh_(gC0), g1v = tanh_(gC1);
        float o0 = sigm(gD0), o1 = sigm(gD1);
        c0 = f0 * c0 + i0 * g0v;
        c1 = f1 * c1 + i1 * g1v;
        float h0 = o0 * tanh_(c0);
        float h1 = o1 * tanh_(c1);
        uint32_t pk = (uint32_t)(uint16_t)f2bf(h0) | ((uint32_t)(uint16_t)f2bf(h1) << 16);
        st_u32((unsigned*)(hb_g + (t & 1) * (MB*H_) + pm * H_ + slice * 32 + pj), pk);
        if (l < 3){
          st_u32((unsigned*)(xout + ((long)(b_base + pm) * T_ + t) * H_ + slice * 32 + pj), pk);
        }
      }

      // ---- Group barrier: drain write-through stores, flag store, poll (no fences) ----
      __asm__ volatile("" ::: "memory");
      __builtin_amdgcn_s_waitcnt(0);       // all h/seq stores reached L3
      __asm__ volatile("" ::: "memory");
      __syncthreads();
      {
        const unsigned step_id = (unsigned)(l * T_ + t + 1);
        if (wave == 0){
          if (lane == 0) st_u32(&flags[slice], step_id);
          if (!dead){
            int guard = 0;
            for (;;){
              unsigned v = ld_u32(&flags[lane & 7]);
              if (__all((int)(v >= step_id))) break;
              if (++guard > (1 << 18)) { dead = true; break; }
            }
          }
        }
      }
      __syncthreads();
    } // t
  } // l
}

// Final FC on last-timestep h of layer 3 (hbuf parity (T_-1)&1 == 1).
__global__ void fc_kernel(const short* __restrict__ hbuf, const float* __restrict__ fcW,
                          const float* __restrict__ fcb, float* __restrict__ out){
  int b = blockIdx.x;
  int lane = threadIdx.x;
  int grp = b >> 4, m = b & 15;
  const short* hp = hbuf + grp * (2 * MB * H_) + (MB * H_) + m * H_;
  float s = 0.f;
  #pragma unroll
  for (int k = 0; k < 4; ++k){
    int j = lane + 64 * k;
    s += bf2f(hp[j]) * fcW[j];
  }
  #pragma unroll
  for (int off = 32; off; off >>= 1) s += __shfl_down(s, off);
  if (lane == 0) out[b] = s + fcb[0];
}

extern "C" void kernel_launch(void* const* d_in, const int* in_sizes, int n_in,
                              void* d_out, int out_size, void* d_ws, size_t ws_size,
                              hipStream_t stream) {
  Params P;
  P.x    = (const float*)d_in[0];
  P.Wih0 = (const float*)d_in[1];  P.Whh0 = (const float*)d_in[2];
  P.bih0 = (const float*)d_in[3];  P.bhh0 = (const float*)d_in[4];
  P.Wih1 = (const float*)d_in[5];  P.Whh1 = (const float*)d_in[6];
  P.bih1 = (const float*)d_in[7];  P.bhh1 = (const float*)d_in[8];
  P.Wih2 = (const float*)d_in[9];  P.Whh2 = (const float*)d_in[10];
  P.bih2 = (const float*)d_in[11]; P.bhh2 = (const float*)d_in[12];
  P.Wih3 = (const float*)d_in[13]; P.Whh3 = (const float*)d_in[14];
  P.bih3 = (const float*)d_in[15]; P.bhh3 = (const float*)d_in[16];
  P.fcW  = (const float*)d_in[17]; P.fcb  = (const float*)d_in[18];

  char* ws = (char*)d_ws;
  P.flags = (unsigned*)ws;                               // 4 KB used
  P.hbuf  = (short*)(ws + 4096);                         // 256 KB
  const size_t SEQ_BYTES = (size_t)B_ * T_ * H_ * 2;     // 64 MB
  P.seq0  = (short*)(ws + (1 << 20));
  P.seq1  = (short*)(ws + (1 << 20) + SEQ_BYTES);

  hipMemsetAsync(P.flags, 0, 4096, stream);
  hipLaunchKernelGGL(lstm_kernel, dim3(NWG), dim3(256), 0, stream, P);
  hipLaunchKernelGGL(fc_kernel, dim3(B_), dim3(64), 0, stream,
                     P.hbuf, P.fcW, P.fcb, (float*)d_out);
}

// Round 5
// 3508.452 us; speedup vs baseline: 8.6922x; 2.0130x over previous
//
#include <hip/hip_runtime.h>
#include <stdint.h>

// Problem constants
#define T_  512
#define H_  256
#define B_  256
#define MB  32      // batch rows per group
#define NGROUP 8    // B_/MB
#define NWG 256     // 8 groups x 4 layers x 8 slices

typedef __attribute__((ext_vector_type(8))) short  short8;   // 8 bf16 = MFMA A/B fragment
typedef __attribute__((ext_vector_type(4))) float  floatx4;  // MFMA C/D fragment

struct Params {
  const float* x;
  const float* Wih[4]; const float* Whh[4]; const float* bih[4]; const float* bhh[4];
  const float* fcW; const float* fcb;
  int*   flags;   // [NGROUP][32] : flags[g*32 + l*8 + slice] = completed steps, one 128B line/group
  short* hbuf;    // [NGROUP][4][2][MB][H_] bf16 ping-pong h per (group,layer)
};

__device__ __forceinline__ short f2bf(float f){
  uint32_t u = __builtin_bit_cast(uint32_t, f);
  u += 0x7fffu + ((u >> 16) & 1u);          // RNE
  return (short)(u >> 16);
}
__device__ __forceinline__ float bf2f(short s){
  uint32_t u = ((uint32_t)(uint16_t)s) << 16;
  return __builtin_bit_cast(float, u);
}
__device__ __forceinline__ float sigm(float v){ return 1.0f / (1.0f + __expf(-v)); }
__device__ __forceinline__ float tanh_(float v){
  float a = fabsf(v);
  float e = __expf(-2.0f * a);
  float r = (1.0f - e) / (1.0f + e);
  return v < 0.0f ? -r : r;
}

// Proven round-2 exchange path: relaxed agent-scope atomics (sc0 sc1 -> coherent at L3,
// no L2 wb/inv fences). Intra-XCD L2 exchange (rounds 3-4) is falsified — do not revisit
// without disasm evidence.
__device__ __forceinline__ unsigned long long a_ld64(const unsigned long long* p){
  return __hip_atomic_load(p, __ATOMIC_RELAXED, __HIP_MEMORY_SCOPE_AGENT);
}
__device__ __forceinline__ void a_st32(unsigned* p, unsigned v){
  __hip_atomic_store(p, v, __ATOMIC_RELAXED, __HIP_MEMORY_SCOPE_AGENT);
}
__device__ __forceinline__ int a_ldi(const int* p){
  return __hip_atomic_load(p, __ATOMIC_RELAXED, __HIP_MEMORY_SCOPE_AGENT);
}
__device__ __forceinline__ void a_sti(int* p, int v){
  __hip_atomic_store(p, v, __ATOMIC_RELAXED, __HIP_MEMORY_SCOPE_AGENT);
}

#define MFMA(a,b,c) __builtin_amdgcn_mfma_f32_16x16x32_bf16((a),(b),(c),0,0,0)

// One pipeline stage: (group g, layer l, slice) for all T steps.
// Slice owns h dims [slice*32, slice*32+32) x all 4 gates; M=32 batch rows (2 M-tiles).
template<bool L0>
__device__ __forceinline__ void run_stage(const Params& p, int g, int l, int slice,
    short* a_frag, float (*g_lds)[MB][33], float (*bias_lds)[32],
    float (*wih0_lds)[32], float* x0_lds)
{
  constexpr int KBT = L0 ? 8 : 16;       // K blocks of 32: h-only (l=0) or x+h
  const int tid = threadIdx.x, lane = tid & 63, wave = tid >> 6;  // wave = gate i,f,g,o
  const int n15 = lane & 15, q4 = lane >> 4;
  const int b_base = g * MB;

  int*   flags   = p.flags + g * 32;
  short* hb_self = p.hbuf + (size_t)((g*4 + l) * 2) * (MB*H_);
  const short* hb_up = L0 ? (const short*)nullptr
                          : p.hbuf + (size_t)((g*4 + l-1) * 2) * (MB*H_);

  const float* WihL = p.Wih[l]; const float* WhhL = p.Whh[l];
  const float* bihL = p.bih[l]; const float* bhhL = p.bhh[l];

  if (tid < 128){
    int gt = tid >> 5, j = tid & 31;
    int gr = gt * 256 + slice * 32 + j;
    bias_lds[gt][j] = bihL[gr] + bhhL[gr];
    if (L0) wih0_lds[gt][j] = WihL[gr];       // W_ih0 is [1024 x 1]
  }

  // ---- Weight B-fragments resident in VGPRs (one-time; plain cached loads) ----
  // kb<8 (l>0): W_ih x-path; kb>=8 (or all for l=0): W_hh h-path.
  short8 wf0[KBT], wf1[KBT];
  const int g0 = wave * 256 + slice * 32 + n15;   // N-tile 0 gate row
  const int g1 = g0 + 16;                         // N-tile 1
  #pragma unroll
  for (int kb = 0; kb < KBT; ++kb){
    const float* base; int kk;
    if (L0)          { base = WhhL; kk = kb * 32 + q4 * 8; }
    else if (kb < 8) { base = WihL; kk = kb * 32 + q4 * 8; }
    else             { base = WhhL; kk = (kb - 8) * 32 + q4 * 8; }
    const float* p0 = base + (size_t)g0 * H_ + kk;
    const float* p1 = base + (size_t)g1 * H_ + kk;
    short8 a, b;
    #pragma unroll
    for (int i = 0; i < 8; ++i){ a[i] = f2bf(p0[i]); b[i] = f2bf(p1[i]); }
    wf0[kb] = a; wf1[kb] = b;
  }

  // cell state: 2 rows x 2 cols per thread
  float c00 = 0.f, c01 = 0.f, c10 = 0.f, c11 = 0.f;
  const int r0 = (tid >> 4) * 2, r1 = r0 + 1;   // batch rows
  const int pc = (tid & 15) * 2;                // h cols (within slice's 32)

  // Dependency thresholds, one flag dword per wave-0 lane (whole group in one line):
  //   own stage >= t (siblings done t-1), upstream >= t+1 (h(t) ready),
  //   downstream >= t-1 (consumed h(t-2); parity-2 write throttle).
  const int fidx = lane & 31;
  const int fl   = fidx >> 3;
  const int dthr = (fl == l) ? 0 : (fl == l - 1) ? 1 : (fl == l + 1) ? -1 : -(1 << 30);
  const int* fp  = flags + fidx;
  bool dead = false;

  const int HROW0 = L0 ? 0 : 16;   // first a_frag row of the h-part

  for (int t = 0; t < T_; ++t){
    // ---- Wait for dependencies (single coalesced poll over the group's flag line) ----
    if (wave == 0 && !dead){
      const int thr = t + dthr;
      int guard = 0;
      for (;;){
        int v = a_ldi(fp);
        if (__all((int)(v >= thr))) break;
        if (++guard > (1 << 16)) { dead = true; break; }   // bail, don't hang
      }
    }
    __syncthreads();

    // ---- Stage A fragments: issue all L3 loads, then LDS stores ----
    {
      unsigned long long hv[8];
      if (t > 0){
        const short* hb = hb_self + ((t - 1) & 1) * (MB*H_);
        #pragma unroll
        for (int i = 0; i < 4; ++i){
          int r = wave * 4 + i;                  // local h row index 0..15
          int kb = r >> 1, mt = r & 1;
          const unsigned long long* src = (const unsigned long long*)
            (hb + (mt * 16 + n15) * H_ + kb * 32 + q4 * 8);
          hv[2*i]   = a_ld64(src);
          hv[2*i+1] = a_ld64(src + 1);
        }
      } else {
        #pragma unroll
        for (int i = 0; i < 8; ++i) hv[i] = 0ull;
      }
      unsigned long long xv[8];
      if (!L0){
        const short* xb = hb_up + (t & 1) * (MB*H_);
        #pragma unroll
        for (int i = 0; i < 4; ++i){
          int r = wave * 4 + i;                  // x rows 0..15
          int kb = r >> 1, mt = r & 1;
          const unsigned long long* src = (const unsigned long long*)
            (xb + (mt * 16 + n15) * H_ + kb * 32 + q4 * 8);
          xv[2*i]   = a_ld64(src);
          xv[2*i+1] = a_ld64(src + 1);
        }
      }
      #pragma unroll
      for (int i = 0; i < 4; ++i){
        int r = HROW0 + wave * 4 + i;
        unsigned long long* d = (unsigned long long*)&a_frag[r * 512 + lane * 8];
        d[0] = hv[2*i]; d[1] = hv[2*i+1];
      }
      if (!L0){
        #pragma unroll
        for (int i = 0; i < 4; ++i){
          int r = wave * 4 + i;
          unsigned long long* d = (unsigned long long*)&a_frag[r * 512 + lane * 8];
          d[0] = xv[2*i]; d[1] = xv[2*i+1];
        }
      } else if (wave == 0 && lane < MB){
        x0_lds[lane] = p.x[(size_t)(b_base + lane) * T_ + t];
      }
    }
    __syncthreads();

    // ---- MFMA: 2 M-tiles x 2 N-tiles, even/odd split-k chains ----
    floatx4 acc[2][2][2] = {};
    #pragma unroll
    for (int kb = 0; kb < KBT; ++kb){
      #pragma unroll
      for (int mt = 0; mt < 2; ++mt){
        short8 af = *(short8*)&a_frag[(kb * 2 + mt) * 512 + lane * 8];
        int pr = kb & 1;
        acc[mt][0][pr] = MFMA(af, wf0[kb], acc[mt][0][pr]);
        acc[mt][1][pr] = MFMA(af, wf1[kb], acc[mt][1][pr]);
      }
    }
    {
      #pragma unroll
      for (int mt = 0; mt < 2; ++mt){
        floatx4 s0 = acc[mt][0][0] + acc[mt][0][1];
        floatx4 s1 = acc[mt][1][0] + acc[mt][1][1];
        int mrow = mt * 16 + q4 * 4;
        #pragma unroll
        for (int r = 0; r < 4; ++r){
          g_lds[wave][mrow + r][n15]      = s0[r];
          g_lds[wave][mrow + r][16 + n15] = s1[r];
        }
      }
    }
    __syncthreads();

    // ---- Pointwise: gates -> c,h (fp32), store h slice (bf16, L3) ----
    {
      float xs0 = 0.f, xs1 = 0.f;
      if (L0){ xs0 = x0_lds[r0]; xs1 = x0_lds[r1]; }
      #pragma unroll
      for (int rr = 0; rr < 2; ++rr){
        const int row = rr ? r1 : r0;
        const float xs = rr ? xs1 : xs0;
        float gi0 = g_lds[0][row][pc]   + bias_lds[0][pc];
        float gi1 = g_lds[0][row][pc+1] + bias_lds[0][pc+1];
        float gf0 = g_lds[1][row][pc]   + bias_lds[1][pc];
        float gf1 = g_lds[1][row][pc+1] + bias_lds[1][pc+1];
        float gg0 = g_lds[2][row][pc]   + bias_lds[2][pc];
        float gg1 = g_lds[2][row][pc+1] + bias_lds[2][pc+1];
        float go0 = g_lds[3][row][pc]   + bias_lds[3][pc];
        float go1 = g_lds[3][row][pc+1] + bias_lds[3][pc+1];
        if (L0){
          gi0 += xs * wih0_lds[0][pc]; gi1 += xs * wih0_lds[0][pc+1];
          gf0 += xs * wih0_lds[1][pc]; gf1 += xs * wih0_lds[1][pc+1];
          gg0 += xs * wih0_lds[2][pc]; gg1 += xs * wih0_lds[2][pc+1];
          go0 += xs * wih0_lds[3][pc]; go1 += xs * wih0_lds[3][pc+1];
        }
        float i0 = sigm(gi0), i1 = sigm(gi1);
        float f0 = sigm(gf0), f1 = sigm(gf1);
        float gv0 = tanh_(gg0), gv1 = tanh_(gg1);
        float o0 = sigm(go0), o1 = sigm(go1);
        float& ca = rr ? c10 : c00;
        float& cb = rr ? c11 : c01;
        ca = f0 * ca + i0 * gv0;
        cb = f1 * cb + i1 * gv1;
        float h0 = o0 * tanh_(ca);
        float h1 = o1 * tanh_(cb);
        unsigned pk = (unsigned)(uint16_t)f2bf(h0) | ((unsigned)(uint16_t)f2bf(h1) << 16);
        a_st32((unsigned*)(hb_self + (t & 1) * (MB*H_) + row * H_ + slice * 32 + pc), pk);
      }
    }

    // ---- Drain stores to L3, then publish flag (round-2 proven ordering) ----
    __asm__ volatile("" ::: "memory");
    __builtin_amdgcn_s_waitcnt(0);
    __asm__ volatile("" ::: "memory");
    __syncthreads();
    if (tid == 0) a_sti(&flags[l * 8 + slice], t + 1);
  } // t
}

__global__ __launch_bounds__(256, 1) void lstm_kernel(Params p){
  __shared__ short a_frag[32 * 512];          // 32 KB, exact MFMA A-fragment order
  __shared__ float g_lds[4][MB][33];          // 16.9 KB gates, padded
  __shared__ float bias_lds[4][32];
  __shared__ float wih0_lds[4][32];
  __shared__ float x0_lds[MB];

  const int wg    = blockIdx.x;
  const int g     = wg >> 5;        // 0..7 batch group
  const int l     = (wg >> 3) & 3;  // 0..3 layer (pipeline stage)
  const int slice = wg & 7;         // 0..7 h-slice

  if (l == 0) run_stage<true >(p, g, 0, slice, a_frag, g_lds, bias_lds, wih0_lds, x0_lds);
  else        run_stage<false>(p, g, l, slice, a_frag, g_lds, bias_lds, wih0_lds, x0_lds);
}

// Final FC on last-timestep h of layer 3 (parity (T_-1)&1 == 1).
__global__ void fc_kernel(const short* __restrict__ hbuf, const float* __restrict__ fcW,
                          const float* __restrict__ fcb, float* __restrict__ out){
  int b = blockIdx.x;               // 0..255
  int lane = threadIdx.x;           // 64
  int g = b >> 5, m = b & 31;
  const short* hp = hbuf + (size_t)((g * 4 + 3) * 2 + 1) * (MB * H_) + m * H_;
  float s = 0.f;
  #pragma unroll
  for (int k = 0; k < 4; ++k){
    int j = lane + 64 * k;
    s += bf2f(hp[j]) * fcW[j];
  }
  #pragma unroll
  for (int off = 32; off; off >>= 1) s += __shfl_down(s, off);
  if (lane == 0) out[b] = s + fcb[0];
}

extern "C" void kernel_launch(void* const* d_in, const int* in_sizes, int n_in,
                              void* d_out, int out_size, void* d_ws, size_t ws_size,
                              hipStream_t stream) {
  Params P;
  P.x = (const float*)d_in[0];
  for (int l = 0; l < 4; ++l){
    P.Wih[l] = (const float*)d_in[1 + 4*l];
    P.Whh[l] = (const float*)d_in[2 + 4*l];
    P.bih[l] = (const float*)d_in[3 + 4*l];
    P.bhh[l] = (const float*)d_in[4 + 4*l];
  }
  P.fcW = (const float*)d_in[17];
  P.fcb = (const float*)d_in[18];

  char* ws = (char*)d_ws;
  P.flags = (int*)ws;                        // 8 groups x 128 B = 1 KB
  P.hbuf  = (short*)(ws + 4096);             // 8x4x2x32x256 bf16 = 1 MB

  hipMemsetAsync(ws, 0, 4096, stream);
  hipLaunchKernelGGL(lstm_kernel, dim3(NWG), dim3(256), 0, stream, P);
  hipLaunchKernelGGL(fc_kernel, dim3(B_), dim3(64), 0, stream,
                     P.hbuf, P.fcW, P.fcb, (float*)d_out);
}

// Round 6
// 2865.332 us; speedup vs baseline: 10.6432x; 1.2244x over previous
//
#include <hip/hip_runtime.h>
#include <stdint.h>

// Problem constants
#define T_  512
#define H_  256
#define B_  256
#define MB  32      // batch rows per group
#define NGROUP 8    // B_/MB
#define NBUF 4      // h ping-pong depth (parity t&3)
#define NWG 256     // 8 groups x 4 layers x 8 slices

typedef __attribute__((ext_vector_type(8))) short  short8;   // 8 bf16 = MFMA A/B fragment
typedef __attribute__((ext_vector_type(4))) float  floatx4;  // MFMA C/D fragment

struct Params {
  const float* x;
  const float* Wih[4]; const float* Whh[4]; const float* bih[4]; const float* bhh[4];
  const float* fcW; const float* fcb;
  int*   flags;   // [NGROUP][4][32] : one 128B line per (group,layer); [slice] = steps done
  short* hbuf;    // [NGROUP][4][NBUF][MB][H_] bf16 h ring per (group,layer)
};

__device__ __forceinline__ short f2bf(float f){
  uint32_t u = __builtin_bit_cast(uint32_t, f);
  u += 0x7fffu + ((u >> 16) & 1u);          // RNE
  return (short)(u >> 16);
}
__device__ __forceinline__ float bf2f(short s){
  uint32_t u = ((uint32_t)(uint16_t)s) << 16;
  return __builtin_bit_cast(float, u);
}
__device__ __forceinline__ float sigm(float v){ return 1.0f / (1.0f + __expf(-v)); }
__device__ __forceinline__ float tanh_(float v){
  float a = fabsf(v);
  float e = __expf(-2.0f * a);
  float r = (1.0f - e) / (1.0f + e);
  return v < 0.0f ? -r : r;
}

// Proven exchange path (round 2/5): relaxed agent-scope atomics — coherent at L3,
// no L2 wb/inv fences. Intra-XCD sc0 exchange was falsified (rounds 3-4); don't revisit.
__device__ __forceinline__ unsigned long long a_ld64(const unsigned long long* p){
  return __hip_atomic_load(p, __ATOMIC_RELAXED, __HIP_MEMORY_SCOPE_AGENT);
}
__device__ __forceinline__ void a_st32(unsigned* p, unsigned v){
  __hip_atomic_store(p, v, __ATOMIC_RELAXED, __HIP_MEMORY_SCOPE_AGENT);
}
__device__ __forceinline__ int a_ldi(const int* p){
  return __hip_atomic_load(p, __ATOMIC_RELAXED, __HIP_MEMORY_SCOPE_AGENT);
}
__device__ __forceinline__ void a_sti(int* p, int v){
  __hip_atomic_store(p, v, __ATOMIC_RELAXED, __HIP_MEMORY_SCOPE_AGENT);
}

#define MFMA(a,b,c) __builtin_amdgcn_mfma_f32_16x16x32_bf16((a),(b),(c),0,0,0)

// Wave-wide poll: every lane has a pointer and threshold; returns when all satisfied.
__device__ __forceinline__ void poll_ge(const int* p, int thr, bool& dead){
  if (dead) return;
  int guard = 0;
  for (;;){
    int v = a_ldi(p);
    if (__all((int)(v >= thr))) break;
    if (++guard > (1 << 17)) { dead = true; break; }   // bail, don't hang
  }
}

// One pipeline stage: (group g, layer l, slice) for all T steps.
template<bool L0>
__device__ __forceinline__ void run_stage(const Params& p, int g, int l, int slice,
    short* a_frag, float (*g_lds)[MB][33], float (*bias_lds)[32],
    float (*wih0_lds)[32], float* x0_lds)
{
  constexpr int KBT = L0 ? 8 : 16;
  const int tid = threadIdx.x, lane = tid & 63, wave = tid >> 6;  // wave = gate i,f,g,o
  const int n15 = lane & 15, q4 = lane >> 4;
  const int b_base = g * MB;

  int* flags_self = p.flags + (g * 4 + l) * 32;
  int* flags_up   = L0 ? flags_self : p.flags + (g * 4 + l - 1) * 32;
  int* flags_down = (l < 3) ? p.flags + (g * 4 + l + 1) * 32 : flags_self;

  short* hb_self = p.hbuf + (size_t)((g*4 + l) * NBUF) * (MB*H_);
  const short* hb_up = L0 ? (const short*)nullptr
                          : p.hbuf + (size_t)((g*4 + l-1) * NBUF) * (MB*H_);

  const float* WihL = p.Wih[l]; const float* WhhL = p.Whh[l];
  const float* bihL = p.bih[l]; const float* bhhL = p.bhh[l];

  if (tid < 128){
    int gt = tid >> 5, j = tid & 31;
    int gr = gt * 256 + slice * 32 + j;
    bias_lds[gt][j] = bihL[gr] + bhhL[gr];
    if (L0) wih0_lds[gt][j] = WihL[gr];       // W_ih0 is [1024 x 1]
  }

  // ---- Weight B-fragments resident in VGPRs (one-time) ----
  short8 wf0[KBT], wf1[KBT];
  const int g0 = wave * 256 + slice * 32 + n15;   // N-tile 0 gate row
  const int g1 = g0 + 16;                         // N-tile 1
  #pragma unroll
  for (int kb = 0; kb < KBT; ++kb){
    const float* base; int kk;
    if (L0)          { base = WhhL; kk = kb * 32 + q4 * 8; }
    else if (kb < 8) { base = WihL; kk = kb * 32 + q4 * 8; }
    else             { base = WhhL; kk = (kb - 8) * 32 + q4 * 8; }
    const float* p0 = base + (size_t)g0 * H_ + kk;
    const float* p1 = base + (size_t)g1 * H_ + kk;
    short8 a, b;
    #pragma unroll
    for (int i = 0; i < 8; ++i){ a[i] = f2bf(p0[i]); b[i] = f2bf(p1[i]); }
    wf0[kb] = a; wf1[kb] = b;
  }

  float c00 = 0.f, c01 = 0.f, c10 = 0.f, c11 = 0.f;
  const int r0 = (tid >> 4) * 2, r1 = r0 + 1;   // batch rows
  const int pc = (tid & 15) * 2;                // h cols within slice

  // Phase-A poll map (wave 0): lanes 0-7 upstream >= t+1 (l>0); lanes 8-15
  // downstream >= t-3 (l<3, ring overwrite throttle); l==0 folds self>=t into
  // lanes 0-7. Others always-true.
  const int* fpA; int dA;
  if (lane < 8){
    if (L0) { fpA = flags_self + lane; dA = 0; }
    else    { fpA = flags_up   + lane; dA = 1; }
  } else if (lane < 16 && l < 3){
    fpA = flags_down + (lane - 8); dA = -3;
  } else {
    fpA = flags_self + (lane & 7); dA = -(1 << 30);
  }
  const int* fpB = flags_self + (lane & 7);     // phase B: siblings >= t
  bool dead = false;

  for (int t = 0; t < T_; ++t){
    const int pt = t & (NBUF - 1);
    const int pprev = (t - 1) & (NBUF - 1);

    // ---- Phase A: wait upstream/downstream (and self for L0) ----
    if (wave == 0) poll_ge(fpA, t + dA, dead);
    __syncthreads();

    if (!L0){
      // ---- Stage x = upstream h(t) ----
      {
        unsigned long long xv[8];
        const short* xb = hb_up + pt * (MB*H_);
        #pragma unroll
        for (int i = 0; i < 4; ++i){
          int r = wave * 4 + i;                  // x rows 0..15
          int kb = r >> 1, mt = r & 1;
          const unsigned long long* src = (const unsigned long long*)
            (xb + (mt * 16 + n15) * H_ + kb * 32 + q4 * 8);
          xv[2*i]   = a_ld64(src);
          xv[2*i+1] = a_ld64(src + 1);
        }
        #pragma unroll
        for (int i = 0; i < 4; ++i){
          int r = wave * 4 + i;
          unsigned long long* d = (unsigned long long*)&a_frag[r * 512 + lane * 8];
          d[0] = xv[2*i]; d[1] = xv[2*i+1];
        }
      }
      __syncthreads();
    } else if (wave == 0 && lane < MB){
      x0_lds[lane] = p.x[(size_t)(b_base + lane) * T_ + t];
    }

    floatx4 acc[2][2][2] = {};

    if (!L0){
      // ---- x-part MFMAs (kb 0..7) while sibling flags propagate ----
      #pragma unroll
      for (int kb = 0; kb < 8; ++kb){
        #pragma unroll
        for (int mt = 0; mt < 2; ++mt){
          short8 af = *(short8*)&a_frag[(kb * 2 + mt) * 512 + lane * 8];
          int pr = kb & 1;
          acc[mt][0][pr] = MFMA(af, wf0[kb], acc[mt][0][pr]);
          acc[mt][1][pr] = MFMA(af, wf1[kb], acc[mt][1][pr]);
        }
      }
      // ---- Phase B: wait siblings >= t ----
      if (wave == 0) poll_ge(fpB, t, dead);
      __syncthreads();
    }

    // ---- Stage own h(t-1) ----
    {
      constexpr int HROW0 = L0 ? 0 : 16;
      unsigned long long hv[8];
      if (t > 0){
        const short* hb = hb_self + pprev * (MB*H_);
        #pragma unroll
        for (int i = 0; i < 4; ++i){
          int r = wave * 4 + i;
          int kb = r >> 1, mt = r & 1;
          const unsigned long long* src = (const unsigned long long*)
            (hb + (mt * 16 + n15) * H_ + kb * 32 + q4 * 8);
          hv[2*i]   = a_ld64(src);
          hv[2*i+1] = a_ld64(src + 1);
        }
      } else {
        #pragma unroll
        for (int i = 0; i < 8; ++i) hv[i] = 0ull;
      }
      #pragma unroll
      for (int i = 0; i < 4; ++i){
        int r = HROW0 + wave * 4 + i;
        unsigned long long* d = (unsigned long long*)&a_frag[r * 512 + lane * 8];
        d[0] = hv[2*i]; d[1] = hv[2*i+1];
      }
    }
    __syncthreads();

    // ---- h-part MFMAs ----
    {
      constexpr int KB0 = L0 ? 0 : 8;
      #pragma unroll
      for (int kb = KB0; kb < KBT; ++kb){
        #pragma unroll
        for (int mt = 0; mt < 2; ++mt){
          short8 af = *(short8*)&a_frag[(kb * 2 + mt) * 512 + lane * 8];
          int pr = kb & 1;
          acc[mt][0][pr] = MFMA(af, wf0[kb], acc[mt][0][pr]);
          acc[mt][1][pr] = MFMA(af, wf1[kb], acc[mt][1][pr]);
        }
      }
      #pragma unroll
      for (int mt = 0; mt < 2; ++mt){
        floatx4 s0 = acc[mt][0][0] + acc[mt][0][1];
        floatx4 s1 = acc[mt][1][0] + acc[mt][1][1];
        int mrow = mt * 16 + q4 * 4;
        #pragma unroll
        for (int r = 0; r < 4; ++r){
          g_lds[wave][mrow + r][n15]      = s0[r];
          g_lds[wave][mrow + r][16 + n15] = s1[r];
        }
      }
    }
    __syncthreads();

    // ---- Pointwise: gates -> c,h (fp32), store h slice (bf16 -> L3) ----
    {
      float xs0 = 0.f, xs1 = 0.f;
      if (L0){ xs0 = x0_lds[r0]; xs1 = x0_lds[r1]; }
      #pragma unroll
      for (int rr = 0; rr < 2; ++rr){
        const int row = rr ? r1 : r0;
        const float xs = rr ? xs1 : xs0;
        float gi0 = g_lds[0][row][pc]   + bias_lds[0][pc];
        float gi1 = g_lds[0][row][pc+1] + bias_lds[0][pc+1];
        float gf0 = g_lds[1][row][pc]   + bias_lds[1][pc];
        float gf1 = g_lds[1][row][pc+1] + bias_lds[1][pc+1];
        float gg0 = g_lds[2][row][pc]   + bias_lds[2][pc];
        float gg1 = g_lds[2][row][pc+1] + bias_lds[2][pc+1];
        float go0 = g_lds[3][row][pc]   + bias_lds[3][pc];
        float go1 = g_lds[3][row][pc+1] + bias_lds[3][pc+1];
        if (L0){
          gi0 += xs * wih0_lds[0][pc]; gi1 += xs * wih0_lds[0][pc+1];
          gf0 += xs * wih0_lds[1][pc]; gf1 += xs * wih0_lds[1][pc+1];
          gg0 += xs * wih0_lds[2][pc]; gg1 += xs * wih0_lds[2][pc+1];
          go0 += xs * wih0_lds[3][pc]; go1 += xs * wih0_lds[3][pc+1];
        }
        float i0 = sigm(gi0), i1 = sigm(gi1);
        float f0 = sigm(gf0), f1 = sigm(gf1);
        float gv0 = tanh_(gg0), gv1 = tanh_(gg1);
        float o0 = sigm(go0), o1 = sigm(go1);
        float& ca = rr ? c10 : c00;
        float& cb = rr ? c11 : c01;
        ca = f0 * ca + i0 * gv0;
        cb = f1 * cb + i1 * gv1;
        float h0 = o0 * tanh_(ca);
        float h1 = o1 * tanh_(cb);
        unsigned pk = (unsigned)(uint16_t)f2bf(h0) | ((unsigned)(uint16_t)f2bf(h1) << 16);
        a_st32((unsigned*)(hb_self + pt * (MB*H_) + row * H_ + slice * 32 + pc), pk);
      }
    }

    // ---- Drain stores to L3 (all waves), then publish flag ----
    __asm__ volatile("" ::: "memory");
    __builtin_amdgcn_s_waitcnt(0);
    __asm__ volatile("" ::: "memory");
    __syncthreads();
    if (tid == 0) a_sti(flags_self + slice, t + 1);
  } // t
}

__global__ __launch_bounds__(256, 1) void lstm_kernel(Params p){
  __shared__ short a_frag[32 * 512];          // 32 KB, exact MFMA A-fragment order
  __shared__ float g_lds[4][MB][33];          // gates, padded
  __shared__ float bias_lds[4][32];
  __shared__ float wih0_lds[4][32];
  __shared__ float x0_lds[MB];

  const int wg    = blockIdx.x;
  const int g     = wg >> 5;        // 0..7 batch group
  const int l     = (wg >> 3) & 3;  // 0..3 layer (pipeline stage)
  const int slice = wg & 7;         // 0..7 h-slice

  if (l == 0) run_stage<true >(p, g, 0, slice, a_frag, g_lds, bias_lds, wih0_lds, x0_lds);
  else        run_stage<false>(p, g, l, slice, a_frag, g_lds, bias_lds, wih0_lds, x0_lds);
}

// Final FC on last-timestep h of layer 3 (ring slot (T_-1)&3 == 3).
__global__ void fc_kernel(const short* __restrict__ hbuf, const float* __restrict__ fcW,
                          const float* __restrict__ fcb, float* __restrict__ out){
  int b = blockIdx.x;               // 0..255
  int lane = threadIdx.x;           // 64
  int g = b >> 5, m = b & 31;
  const short* hp = hbuf + (size_t)((g * 4 + 3) * NBUF + ((T_-1) & (NBUF-1))) * (MB * H_)
                  + m * H_;
  float s = 0.f;
  #pragma unroll
  for (int k = 0; k < 4; ++k){
    int j = lane + 64 * k;
    s += bf2f(hp[j]) * fcW[j];
  }
  #pragma unroll
  for (int off = 32; off; off >>= 1) s += __shfl_down(s, off);
  if (lane == 0) out[b] = s + fcb[0];
}

extern "C" void kernel_launch(void* const* d_in, const int* in_sizes, int n_in,
                              void* d_out, int out_size, void* d_ws, size_t ws_size,
                              hipStream_t stream) {
  Params P;
  P.x = (const float*)d_in[0];
  for (int l = 0; l < 4; ++l){
    P.Wih[l] = (const float*)d_in[1 + 4*l];
    P.Whh[l] = (const float*)d_in[2 + 4*l];
    P.bih[l] = (const float*)d_in[3 + 4*l];
    P.bhh[l] = (const float*)d_in[4 + 4*l];
  }
  P.fcW = (const float*)d_in[17];
  P.fcb = (const float*)d_in[18];

  char* ws = (char*)d_ws;
  P.flags = (int*)ws;                        // 8 groups x 4 layers x 128 B = 4 KB
  P.hbuf  = (short*)(ws + 8192);             // 8x4x4x32x256 bf16 = 2 MB

  hipMemsetAsync(ws, 0, 8192, stream);
  hipLaunchKernelGGL(lstm_kernel, dim3(NWG), dim3(256), 0, stream, P);
  hipLaunchKernelGGL(fc_kernel, dim3(B_), dim3(64), 0, stream,
                     P.hbuf, P.fcW, P.fcb, (float*)d_out);
}